// Round 9
// baseline (51.337 us; speedup 1.0000x reference)
//
#include <hip/hip_runtime.h>

// Peg-solitaire batched env step — cell-space atomic bitboard + NONTEMPORAL
// bulk stores. n = 262144. Identical to R7 except the pegs/states store
// sites use __builtin_nontemporal_store (isolated A/B on the nt variable).
//
// Inputs: 0 pegs f32(n,33) | 1 n_pegs i32(n) | 2 done bool(n)
//         3 total_reward f32(n) | 4 actions i32(n)
//         5 pos_ids(132) | 6 mid_idx(132) | 7 tgt_idx(132) (OOB->0 encoded)
//         8 oob (unused) | 9 i_ind (unused) | 10 j_ind (unused)
// Output flat f32 (184n): rewards[0,n) | states[n,148n) | done[148n,149n)
//  | pegs[149n,182n) | n_pegs[182n,183n) | total_reward[183n,184n)

#define NTH 256
#define WPB 4      // waves per block
#define EPW 64     // envs per wave

typedef float f32x4 __attribute__((ext_vector_type(4)));

// cell k -> grid bit (i*7+j); used ONLY with compile-time (unrolled) indices.
__device__ constexpr int C2B[33] = {
    24,  2,  3,  4,  9, 10, 11, 14, 15, 16, 17, 18, 19, 20,
    21, 22, 23, 25, 26, 27, 28, 29, 30, 31, 32, 33, 34,
    37, 38, 39, 44, 45, 46};

constexpr unsigned long long MASK33 = (1ull << 33) - 1;

constexpr unsigned long long cross_mask() {
    unsigned long long b = 0;
    for (int i = 0; i < 7; ++i)
        for (int j = 0; j < 7; ++j)
            if ((i >= 2 && i <= 4) || (j >= 2 && j <= 4))
                b |= 1ull << (i * 7 + j);
    return b;
}
constexpr unsigned long long cols_le(int jmax) {
    unsigned long long b = 0;
    for (int i = 0; i < 7; ++i)
        for (int j = 0; j <= jmax; ++j) b |= 1ull << (i * 7 + j);
    return b;
}
constexpr unsigned long long cols_ge(int jmin) {
    unsigned long long b = 0;
    for (int i = 0; i < 7; ++i)
        for (int j = jmin; j < 7; ++j) b |= 1ull << (i * 7 + j);
    return b;
}
constexpr unsigned long long B_MASK = cross_mask();
constexpr unsigned long long C_LE4  = cols_le(4);   // sources of j+1 jumps
constexpr unsigned long long C_GE2  = cols_ge(2);   // sources of j-1 jumps

// Intra-wave LDS fence: all prior ds ops by this wave complete & visible.
__device__ __forceinline__ void wave_lds_fence() {
    asm volatile("s_waitcnt lgkmcnt(0)" ::: "memory");
    __builtin_amdgcn_sched_barrier(0);   // rule #18 insurance
}

__global__ __launch_bounds__(NTH, 6) void peg_step(
    const float* __restrict__ pegs_in,
    const int* __restrict__ n_pegs_in,
    const unsigned char* __restrict__ done_in,
    const float* __restrict__ tot_rew_in,
    const int* __restrict__ actions,
    const int* __restrict__ pos_ids,
    const int* __restrict__ mid_idx,
    const int* __restrict__ tgt_idx,
    float* __restrict__ out,
    int n)
{
    __shared__ unsigned long long s_cm[WPB][EPW + 1];   // cell masks (+pad)
    __shared__ unsigned long long s_bb[WPB][EPW];       // grid masks
    __shared__ float s_r1[WPB][EPW], s_r2[WPB][EPW];

    const int t    = threadIdx.x;
    const int w    = t >> 6;
    const int lane = t & 63;
    const int ew0  = blockIdx.x * (WPB * EPW) + w * EPW;   // wave's first env
    const int e    = ew0 + lane;

    // Zero own accumulator (DS ops in-order per wave; atomics follow in
    // program order -> no fence needed here).
    s_cm[w][lane] = 0ull;

    // ---- Staging: 9 coalesced f4 loads, all independent, issued early.
    const f32x4* src = (const f32x4*)(pegs_in + (size_t)ew0 * 33);
    f32x4 r[8], r8;
    #pragma unroll
    for (int k = 0; k < 8; ++k) r[k] = src[lane + 64 * k];   // 528 = 8*64+16
    if (lane < 16) r8 = src[512 + lane];

    // ---- Scalar loads + early scalar outputs (fill the load bubble).
    const int a         = actions[e];
    const int np_new    = n_pegs_in[e] - 1;
    const bool done_old = (done_in[e] != 0);
    const float tot     = tot_rew_in[e];
    const int p = pos_ids[a], m = mid_idx[a], g = tgt_idx[a];   // OOB->0

    const float rw  = (np_new == 1) ? 1.0f : (1.0f / 31.0f);
    const float npf = (float)np_new;
    out[e]                   = rw;          // rewards
    out[(size_t)182 * n + e] = npf;         // n_pegs
    out[(size_t)183 * n + e] = tot + rw;    // total_reward

    // ---- Accumulate cell-mask bits: one ds_or_b64 per chunk (+1 on chunks
    //      straddling an env boundary).
    {
        unsigned long long* cm = s_cm[w];
        #pragma unroll
        for (int k = 0; k < 8; ++k) {
            const int q   = lane + 64 * k;
            const int f   = q * 4;
            const int env = f / 33;                  // magic-mul (const div)
            const int c   = f - env * 33;
            const unsigned mm = (r[k][0] != 0.0f) | ((r[k][1] != 0.0f) << 1) |
                                ((r[k][2] != 0.0f) << 2) | ((r[k][3] != 0.0f) << 3);
            const unsigned long long full = (unsigned long long)mm << c;
            atomicOr(&cm[env], full & MASK33);
            const unsigned long long hi = full >> 33;
            if (hi) atomicOr(&cm[env + 1], hi);
        }
        if (lane < 16) {
            const int q   = 512 + lane;
            const int f   = q * 4;
            const int env = f / 33;
            const int c   = f - env * 33;
            const unsigned mm = (r8[0] != 0.0f) | ((r8[1] != 0.0f) << 1) |
                                ((r8[2] != 0.0f) << 2) | ((r8[3] != 0.0f) << 3);
            const unsigned long long full = (unsigned long long)mm << c;
            atomicOr(&cm[env], full & MASK33);
            const unsigned long long hi = full >> 33;
            if (hi) atomicOr(&cm[env + 1], hi);
        }
    }

    wave_lds_fence();   // all lanes' ORs into this wave's segment complete

    // ---- Own-env cell mask: patch jump in CELL space.
    //      order pos<-0, mid<-0, tgt<-1 (aliasing when OOB defaults to 0)
    unsigned long long cm = s_cm[w][lane];
    cm &= ~(1ull << p);
    cm &= ~(1ull << m);
    cm |=  (1ull << g);

    // ---- Cell -> grid conversion (compile-time shifts), feasibility.
    unsigned long long P = 0;
    #pragma unroll
    for (int c = 0; c < 33; ++c)
        P |= ((cm >> c) & 1ull) << C2B[c];

    const unsigned long long E = ~P & B_MASK;
    const unsigned long long feas =
        (P & (P >> 1) & (E >> 2)  & C_LE4) |   // j+1
        (P & (P << 1) & (E << 2)  & C_GE2) |   // j-1
        (P & (P >> 7) & (E >> 14))         |   // i+1
        (P & (P << 7) & (E << 14));            // i-1

    const bool dn = (np_new == 1) | done_old | (feas == 0ull);
    out[(size_t)148 * n + e] = dn ? 1.0f : 0.0f;    // done

    s_cm[w][lane] = cm;                              // patched, for pegs-out
    s_bb[w][lane] = P;                               // grid, for states ch0
    s_r1[w][lane] = (npf - 1.0f)  * (1.0f / 31.0f);  // peg_ratio
    s_r2[w][lane] = (32.0f - npf) * (1.0f / 31.0f);  // removed_ratio

    wave_lds_fence();   // patched masks + ratios visible wave-wide

    // ---- pegs out: regenerate from patched cell masks — NONTEMPORAL.
    {
        f32x4* dst = (f32x4*)(out + (size_t)149 * n + (size_t)ew0 * 33);
        #pragma unroll
        for (int k = 0; k < 9; ++k) {
            const int q = lane + 64 * k;
            if (k < 8 || lane < 16) {                // q < 528
                const int f   = q * 4;
                const int env = f / 33;              // magic-mul
                const int c   = f - env * 33;
                const unsigned long long cat =
                    s_cm[w][env] | (s_cm[w][env + 1] << 33);
                f32x4 v;
                #pragma unroll
                for (int rr = 0; rr < 4; ++rr)
                    v[rr] = (float)((unsigned int)(cat >> (c + rr)) & 1u);
                __builtin_nontemporal_store(v, dst + q);
            }
        }
    }

    // ---- States (env,7,7,3): same math as R7 — NONTEMPORAL stores.
    {
        f32x4* dst = (f32x4*)(out + (size_t)n + (size_t)ew0 * 147);
        const int total = EPW * 147 / 4;              // 2352
        for (int q = lane; q < total; q += 64) {
            const int f4 = q * 4;
            int env = f4 / 147;                       // magic-mul
            int el  = f4 - env * 147;
            unsigned long long bb = s_bb[w][env];
            float r1 = s_r1[w][env], r2 = s_r2[w][env];
            f32x4 v;
            #pragma unroll
            for (int rr = 0; rr < 4; ++rr) {
                if (el == 147) {                      // env boundary
                    el = 0; ++env;
                    bb = s_bb[w][env]; r1 = s_r1[w][env]; r2 = s_r2[w][env];
                }
                const int rc = el / 3;                // magic-mul
                const int ch = el - rc * 3;
                v[rr] = (ch == 0) ? (float)((unsigned int)(bb >> rc) & 1u)
                                  : ((ch == 1) ? r1 : r2);
                ++el;
            }
            __builtin_nontemporal_store(v, dst + q);
        }
    }
}

extern "C" void kernel_launch(void* const* d_in, const int* in_sizes, int n_in,
                              void* d_out, int out_size, void* d_ws, size_t ws_size,
                              hipStream_t stream) {
    const float* pegs          = (const float*)d_in[0];
    const int* n_pegs          = (const int*)d_in[1];
    const unsigned char* done  = (const unsigned char*)d_in[2];
    const float* total_reward  = (const float*)d_in[3];
    const int* actions         = (const int*)d_in[4];
    const int* pos_ids         = (const int*)d_in[5];
    const int* mid_idx         = (const int*)d_in[6];
    const int* tgt_idx         = (const int*)d_in[7];
    // d_in[8] oob_mask, d_in[9] i_ind, d_in[10] j_ind: unused.
    float* out = (float*)d_out;

    int n = in_sizes[1];                    // 262144, divisible by 256
    dim3 grid(n / (WPB * EPW)), block(NTH);
    hipLaunchKernelGGL(peg_step, grid, block, 0, stream,
                       pegs, n_pegs, done, total_reward, actions,
                       pos_ids, mid_idx, tgt_idx, out, n);
}

// Round 10
// 48.318 us; speedup vs baseline: 1.0625x; 1.0625x over previous
//
#include <hip/hip_runtime.h>

// Peg-solitaire batched env step — KERNEL FISSION edition. n = 262144.
// K1 (compute): reads all inputs (~39 MB), writes 4 scalar outputs (4 MB) +
//   per-env patched 33-bit cell mask to d_ws (2 MB). Mixed small streams.
// K2 (stream): reads ws records (2 MB) + n_pegs_out (1 MB), regenerates and
//   streams pegs_out (35 MB) + states (154 MB) — nearly pure-write, 2 streams,
//   should run near fill rate (~7 TB/s).
// All building blocks verbatim from R7 (44.8 us); nt stores reverted (R8: -15%).
//
// Inputs: 0 pegs f32(n,33) | 1 n_pegs i32(n) | 2 done bool(n)
//         3 total_reward f32(n) | 4 actions i32(n)
//         5 pos_ids(132) | 6 mid_idx(132) | 7 tgt_idx(132) (OOB->0 encoded)
//         8 oob (unused) | 9 i_ind (unused) | 10 j_ind (unused)
// Output flat f32 (184n): rewards[0,n) | states[n,148n) | done[148n,149n)
//  | pegs[149n,182n) | n_pegs[182n,183n) | total_reward[183n,184n)

#define NTH 256
#define WPB 4      // waves per block
#define EPW 64     // envs per wave

typedef float f32x4 __attribute__((ext_vector_type(4)));

// cell k -> grid bit (i*7+j); used ONLY with compile-time (unrolled) indices.
__device__ constexpr int C2B[33] = {
    24,  2,  3,  4,  9, 10, 11, 14, 15, 16, 17, 18, 19, 20,
    21, 22, 23, 25, 26, 27, 28, 29, 30, 31, 32, 33, 34,
    37, 38, 39, 44, 45, 46};

constexpr unsigned long long MASK33 = (1ull << 33) - 1;

constexpr unsigned long long cross_mask() {
    unsigned long long b = 0;
    for (int i = 0; i < 7; ++i)
        for (int j = 0; j < 7; ++j)
            if ((i >= 2 && i <= 4) || (j >= 2 && j <= 4))
                b |= 1ull << (i * 7 + j);
    return b;
}
constexpr unsigned long long cols_le(int jmax) {
    unsigned long long b = 0;
    for (int i = 0; i < 7; ++i)
        for (int j = 0; j <= jmax; ++j) b |= 1ull << (i * 7 + j);
    return b;
}
constexpr unsigned long long cols_ge(int jmin) {
    unsigned long long b = 0;
    for (int i = 0; i < 7; ++i)
        for (int j = jmin; j < 7; ++j) b |= 1ull << (i * 7 + j);
    return b;
}
constexpr unsigned long long B_MASK = cross_mask();
constexpr unsigned long long C_LE4  = cols_le(4);
constexpr unsigned long long C_GE2  = cols_ge(2);

__device__ __forceinline__ void wave_lds_fence() {
    asm volatile("s_waitcnt lgkmcnt(0)" ::: "memory");
    __builtin_amdgcn_sched_barrier(0);
}

// Cell mask -> grid mask (compile-time shifts).
__device__ __forceinline__ unsigned long long cm_to_grid(unsigned long long cm) {
    unsigned long long P = 0;
    #pragma unroll
    for (int c = 0; c < 33; ++c)
        P |= ((cm >> c) & 1ull) << C2B[c];
    return P;
}

// ============================ K1: compute ================================
__global__ __launch_bounds__(NTH) void peg_compute(
    const float* __restrict__ pegs_in,
    const int* __restrict__ n_pegs_in,
    const unsigned char* __restrict__ done_in,
    const float* __restrict__ tot_rew_in,
    const int* __restrict__ actions,
    const int* __restrict__ pos_ids,
    const int* __restrict__ mid_idx,
    const int* __restrict__ tgt_idx,
    float* __restrict__ out,
    unsigned long long* __restrict__ ws_cm,
    int n)
{
    __shared__ unsigned long long s_cm[WPB][EPW + 1];

    const int t    = threadIdx.x;
    const int w    = t >> 6;
    const int lane = t & 63;
    const int ew0  = blockIdx.x * (WPB * EPW) + w * EPW;
    const int e    = ew0 + lane;

    s_cm[w][lane] = 0ull;   // DS in-order per wave: zeros precede atomics

    // 9 coalesced f4 loads, all independent.
    const f32x4* src = (const f32x4*)(pegs_in + (size_t)ew0 * 33);
    f32x4 r[8], r8;
    #pragma unroll
    for (int k = 0; k < 8; ++k) r[k] = src[lane + 64 * k];   // 528 = 8*64+16
    if (lane < 16) r8 = src[512 + lane];

    const int a         = actions[e];
    const int np_new    = n_pegs_in[e] - 1;
    const bool done_old = (done_in[e] != 0);
    const float tot     = tot_rew_in[e];
    const int p = pos_ids[a], m = mid_idx[a], g = tgt_idx[a];   // OOB->0

    const float rw  = (np_new == 1) ? 1.0f : (1.0f / 31.0f);
    const float npf = (float)np_new;
    out[e]                   = rw;          // rewards
    out[(size_t)182 * n + e] = npf;         // n_pegs
    out[(size_t)183 * n + e] = tot + rw;    // total_reward

    // Accumulate cell-mask bits (ds_or_b64 per chunk).
    {
        unsigned long long* cm = s_cm[w];
        #pragma unroll
        for (int k = 0; k < 8; ++k) {
            const int q   = lane + 64 * k;
            const int f   = q * 4;
            const int env = f / 33;
            const int c   = f - env * 33;
            const unsigned mm = (r[k][0] != 0.0f) | ((r[k][1] != 0.0f) << 1) |
                                ((r[k][2] != 0.0f) << 2) | ((r[k][3] != 0.0f) << 3);
            const unsigned long long full = (unsigned long long)mm << c;
            atomicOr(&cm[env], full & MASK33);
            const unsigned long long hi = full >> 33;
            if (hi) atomicOr(&cm[env + 1], hi);
        }
        if (lane < 16) {
            const int q   = 512 + lane;
            const int f   = q * 4;
            const int env = f / 33;
            const int c   = f - env * 33;
            const unsigned mm = (r8[0] != 0.0f) | ((r8[1] != 0.0f) << 1) |
                                ((r8[2] != 0.0f) << 2) | ((r8[3] != 0.0f) << 3);
            const unsigned long long full = (unsigned long long)mm << c;
            atomicOr(&cm[env], full & MASK33);
            const unsigned long long hi = full >> 33;
            if (hi) atomicOr(&cm[env + 1], hi);
        }
    }

    wave_lds_fence();

    // Patch jump in cell space: order pos<-0, mid<-0, tgt<-1.
    unsigned long long cm = s_cm[w][lane];
    cm &= ~(1ull << p);
    cm &= ~(1ull << m);
    cm |=  (1ull << g);

    const unsigned long long P = cm_to_grid(cm);
    const unsigned long long E = ~P & B_MASK;
    const unsigned long long feas =
        (P & (P >> 1) & (E >> 2)  & C_LE4) |
        (P & (P << 1) & (E << 2)  & C_GE2) |
        (P & (P >> 7) & (E >> 14))         |
        (P & (P << 7) & (E << 14));

    const bool dn = (np_new == 1) | done_old | (feas == 0ull);
    out[(size_t)148 * n + e] = dn ? 1.0f : 0.0f;    // done

    ws_cm[e] = cm;                                   // 8 B/env record
}

// ============================ K2: stream =================================
__global__ __launch_bounds__(NTH) void peg_stream(
    const unsigned long long* __restrict__ ws_cm,
    const float* __restrict__ npf_src,      // = out + 182n (written by K1)
    float* __restrict__ out,
    int n)
{
    __shared__ unsigned long long s_cm[WPB][EPW + 1];   // +pad (addressable)
    __shared__ unsigned long long s_bb[WPB][EPW];
    __shared__ float s_r1[WPB][EPW], s_r2[WPB][EPW];

    const int t    = threadIdx.x;
    const int w    = t >> 6;
    const int lane = t & 63;
    const int ew0  = blockIdx.x * (WPB * EPW) + w * EPW;
    const int e    = ew0 + lane;

    const unsigned long long cm = ws_cm[e];          // coalesced 8 B/lane
    const float npf = npf_src[e];                    // coalesced 4 B/lane

    s_cm[w][lane] = cm;
    s_bb[w][lane] = cm_to_grid(cm);
    s_r1[w][lane] = (npf - 1.0f)  * (1.0f / 31.0f);
    s_r2[w][lane] = (32.0f - npf) * (1.0f / 31.0f);

    wave_lds_fence();

    // pegs out: regenerate from patched cell masks (values are {0,1}).
    {
        f32x4* dst = (f32x4*)(out + (size_t)149 * n + (size_t)ew0 * 33);
        #pragma unroll
        for (int k = 0; k < 9; ++k) {
            const int q = lane + 64 * k;
            if (k < 8 || lane < 16) {                // q < 528
                const int f   = q * 4;
                const int env = f / 33;
                const int c   = f - env * 33;
                const unsigned long long cat =
                    s_cm[w][env] | (s_cm[w][env + 1] << 33);
                f32x4 v;
                #pragma unroll
                for (int rr = 0; rr < 4; ++rr)
                    v[rr] = (float)((unsigned int)(cat >> (c + rr)) & 1u);
                dst[q] = v;
            }
        }
    }

    // states (env,7,7,3): el = rc*3+ch; ch0 = grid bit rc; ch1/ch2 ratios.
    {
        f32x4* dst = (f32x4*)(out + (size_t)n + (size_t)ew0 * 147);
        const int total = EPW * 147 / 4;              // 2352
        for (int q = lane; q < total; q += 64) {
            const int f4 = q * 4;
            int env = f4 / 147;
            int el  = f4 - env * 147;
            unsigned long long bb = s_bb[w][env];
            float r1 = s_r1[w][env], r2 = s_r2[w][env];
            f32x4 v;
            #pragma unroll
            for (int rr = 0; rr < 4; ++rr) {
                if (el == 147) {
                    el = 0; ++env;
                    bb = s_bb[w][env]; r1 = s_r1[w][env]; r2 = s_r2[w][env];
                }
                const int rc = el / 3;
                const int ch = el - rc * 3;
                v[rr] = (ch == 0) ? (float)((unsigned int)(bb >> rc) & 1u)
                                  : ((ch == 1) ? r1 : r2);
                ++el;
            }
            dst[q] = v;
        }
    }
}

// ================= Fallback: monolithic (R7, 44.8 us) ====================
__global__ __launch_bounds__(NTH) void peg_mono(
    const float* __restrict__ pegs_in,
    const int* __restrict__ n_pegs_in,
    const unsigned char* __restrict__ done_in,
    const float* __restrict__ tot_rew_in,
    const int* __restrict__ actions,
    const int* __restrict__ pos_ids,
    const int* __restrict__ mid_idx,
    const int* __restrict__ tgt_idx,
    float* __restrict__ out,
    int n)
{
    __shared__ unsigned long long s_cm[WPB][EPW + 1];
    __shared__ unsigned long long s_bb[WPB][EPW];
    __shared__ float s_r1[WPB][EPW], s_r2[WPB][EPW];

    const int t    = threadIdx.x;
    const int w    = t >> 6;
    const int lane = t & 63;
    const int ew0  = blockIdx.x * (WPB * EPW) + w * EPW;
    const int e    = ew0 + lane;

    s_cm[w][lane] = 0ull;

    const f32x4* src = (const f32x4*)(pegs_in + (size_t)ew0 * 33);
    f32x4 r[8], r8;
    #pragma unroll
    for (int k = 0; k < 8; ++k) r[k] = src[lane + 64 * k];
    if (lane < 16) r8 = src[512 + lane];

    const int a         = actions[e];
    const int np_new    = n_pegs_in[e] - 1;
    const bool done_old = (done_in[e] != 0);
    const float tot     = tot_rew_in[e];
    const int p = pos_ids[a], m = mid_idx[a], g = tgt_idx[a];

    const float rw  = (np_new == 1) ? 1.0f : (1.0f / 31.0f);
    const float npf = (float)np_new;
    out[e]                   = rw;
    out[(size_t)182 * n + e] = npf;
    out[(size_t)183 * n + e] = tot + rw;

    {
        unsigned long long* cm = s_cm[w];
        #pragma unroll
        for (int k = 0; k < 8; ++k) {
            const int q   = lane + 64 * k;
            const int f   = q * 4;
            const int env = f / 33;
            const int c   = f - env * 33;
            const unsigned mm = (r[k][0] != 0.0f) | ((r[k][1] != 0.0f) << 1) |
                                ((r[k][2] != 0.0f) << 2) | ((r[k][3] != 0.0f) << 3);
            const unsigned long long full = (unsigned long long)mm << c;
            atomicOr(&cm[env], full & MASK33);
            const unsigned long long hi = full >> 33;
            if (hi) atomicOr(&cm[env + 1], hi);
        }
        if (lane < 16) {
            const int q   = 512 + lane;
            const int f   = q * 4;
            const int env = f / 33;
            const int c   = f - env * 33;
            const unsigned mm = (r8[0] != 0.0f) | ((r8[1] != 0.0f) << 1) |
                                ((r8[2] != 0.0f) << 2) | ((r8[3] != 0.0f) << 3);
            const unsigned long long full = (unsigned long long)mm << c;
            atomicOr(&cm[env], full & MASK33);
            const unsigned long long hi = full >> 33;
            if (hi) atomicOr(&cm[env + 1], hi);
        }
    }

    wave_lds_fence();

    unsigned long long cm = s_cm[w][lane];
    cm &= ~(1ull << p);
    cm &= ~(1ull << m);
    cm |=  (1ull << g);

    const unsigned long long P = cm_to_grid(cm);
    const unsigned long long E = ~P & B_MASK;
    const unsigned long long feas =
        (P & (P >> 1) & (E >> 2)  & C_LE4) |
        (P & (P << 1) & (E << 2)  & C_GE2) |
        (P & (P >> 7) & (E >> 14))         |
        (P & (P << 7) & (E << 14));

    const bool dn = (np_new == 1) | done_old | (feas == 0ull);
    out[(size_t)148 * n + e] = dn ? 1.0f : 0.0f;

    s_cm[w][lane] = cm;
    s_bb[w][lane] = P;
    s_r1[w][lane] = (npf - 1.0f)  * (1.0f / 31.0f);
    s_r2[w][lane] = (32.0f - npf) * (1.0f / 31.0f);

    wave_lds_fence();

    {
        f32x4* dst = (f32x4*)(out + (size_t)149 * n + (size_t)ew0 * 33);
        #pragma unroll
        for (int k = 0; k < 9; ++k) {
            const int q = lane + 64 * k;
            if (k < 8 || lane < 16) {
                const int f   = q * 4;
                const int env = f / 33;
                const int c   = f - env * 33;
                const unsigned long long cat =
                    s_cm[w][env] | (s_cm[w][env + 1] << 33);
                f32x4 v;
                #pragma unroll
                for (int rr = 0; rr < 4; ++rr)
                    v[rr] = (float)((unsigned int)(cat >> (c + rr)) & 1u);
                dst[q] = v;
            }
        }
    }
    {
        f32x4* dst = (f32x4*)(out + (size_t)n + (size_t)ew0 * 147);
        const int total = EPW * 147 / 4;
        for (int q = lane; q < total; q += 64) {
            const int f4 = q * 4;
            int env = f4 / 147;
            int el  = f4 - env * 147;
            unsigned long long bb = s_bb[w][env];
            float r1 = s_r1[w][env], r2 = s_r2[w][env];
            f32x4 v;
            #pragma unroll
            for (int rr = 0; rr < 4; ++rr) {
                if (el == 147) {
                    el = 0; ++env;
                    bb = s_bb[w][env]; r1 = s_r1[w][env]; r2 = s_r2[w][env];
                }
                const int rc = el / 3;
                const int ch = el - rc * 3;
                v[rr] = (ch == 0) ? (float)((unsigned int)(bb >> rc) & 1u)
                                  : ((ch == 1) ? r1 : r2);
                ++el;
            }
            dst[q] = v;
        }
    }
}

extern "C" void kernel_launch(void* const* d_in, const int* in_sizes, int n_in,
                              void* d_out, int out_size, void* d_ws, size_t ws_size,
                              hipStream_t stream) {
    const float* pegs          = (const float*)d_in[0];
    const int* n_pegs          = (const int*)d_in[1];
    const unsigned char* done  = (const unsigned char*)d_in[2];
    const float* total_reward  = (const float*)d_in[3];
    const int* actions         = (const int*)d_in[4];
    const int* pos_ids         = (const int*)d_in[5];
    const int* mid_idx         = (const int*)d_in[6];
    const int* tgt_idx         = (const int*)d_in[7];
    float* out = (float*)d_out;

    int n = in_sizes[1];                    // 262144, divisible by 256
    dim3 grid(n / (WPB * EPW)), block(NTH);

    if (ws_size >= (size_t)n * 8) {
        unsigned long long* ws_cm = (unsigned long long*)d_ws;
        hipLaunchKernelGGL(peg_compute, grid, block, 0, stream,
                           pegs, n_pegs, done, total_reward, actions,
                           pos_ids, mid_idx, tgt_idx, out, ws_cm, n);
        hipLaunchKernelGGL(peg_stream, grid, block, 0, stream,
                           ws_cm, out + (size_t)182 * n, out, n);
    } else {
        hipLaunchKernelGGL(peg_mono, grid, block, 0, stream,
                           pegs, n_pegs, done, total_reward, actions,
                           pos_ids, mid_idx, tgt_idx, out, n);
    }
}

// Round 11
// 47.280 us; speedup vs baseline: 1.0858x; 1.0219x over previous
//
#include <hip/hip_runtime.h>

// Peg-solitaire batched env step — 2-tile software-pipelined wave edition.
// n = 262144. Each 64-lane wave owns TWO consecutive 64-env tiles; both
// tiles' global loads are issued before tile A's compute/stores, so tile B's
// read traffic overlaps tile A's store stream (sustained mixed traffic
// instead of device-wide read-burst -> write-burst phases).
// Compute/store bodies identical to R7 (44.8 us). Plain stores (R8: nt -15%).
//
// Inputs: 0 pegs f32(n,33) | 1 n_pegs i32(n) | 2 done bool(n)
//         3 total_reward f32(n) | 4 actions i32(n)
//         5 pos_ids(132) | 6 mid_idx(132) | 7 tgt_idx(132) (OOB->0 encoded)
//         8 oob (unused) | 9 i_ind (unused) | 10 j_ind (unused)
// Output flat f32 (184n): rewards[0,n) | states[n,148n) | done[148n,149n)
//  | pegs[149n,182n) | n_pegs[182n,183n) | total_reward[183n,184n)

#define NTH 256
#define WPB 4      // waves per block
#define EPW 64     // envs per tile
#define TPW 2      // tiles per wave (static 2-stage pipeline, named regs)

typedef float f32x4 __attribute__((ext_vector_type(4)));

// cell k -> grid bit (i*7+j); used ONLY with compile-time (unrolled) indices.
__device__ constexpr int C2B[33] = {
    24,  2,  3,  4,  9, 10, 11, 14, 15, 16, 17, 18, 19, 20,
    21, 22, 23, 25, 26, 27, 28, 29, 30, 31, 32, 33, 34,
    37, 38, 39, 44, 45, 46};

constexpr unsigned long long MASK33 = (1ull << 33) - 1;

constexpr unsigned long long cross_mask() {
    unsigned long long b = 0;
    for (int i = 0; i < 7; ++i)
        for (int j = 0; j < 7; ++j)
            if ((i >= 2 && i <= 4) || (j >= 2 && j <= 4))
                b |= 1ull << (i * 7 + j);
    return b;
}
constexpr unsigned long long cols_le(int jmax) {
    unsigned long long b = 0;
    for (int i = 0; i < 7; ++i)
        for (int j = 0; j <= jmax; ++j) b |= 1ull << (i * 7 + j);
    return b;
}
constexpr unsigned long long cols_ge(int jmin) {
    unsigned long long b = 0;
    for (int i = 0; i < 7; ++i)
        for (int j = jmin; j < 7; ++j) b |= 1ull << (i * 7 + j);
    return b;
}
constexpr unsigned long long B_MASK = cross_mask();
constexpr unsigned long long C_LE4  = cols_le(4);   // sources of j+1 jumps
constexpr unsigned long long C_GE2  = cols_ge(2);   // sources of j-1 jumps

__device__ __forceinline__ void wave_lds_fence() {
    asm volatile("s_waitcnt lgkmcnt(0)" ::: "memory");
    __builtin_amdgcn_sched_barrier(0);   // rule #18 insurance
}

__device__ __forceinline__ unsigned long long cm_to_grid(unsigned long long cm) {
    unsigned long long P = 0;
    #pragma unroll
    for (int c = 0; c < 33; ++c)
        P |= ((cm >> c) & 1ull) << C2B[c];
    return P;
}

struct TileRegs {
    f32x4 r[8];
    f32x4 r8;
    int a, np_new, p, m, g;
    bool done_old;
    float tot;
};

__device__ __forceinline__ void load_tile(
    TileRegs& T, int ew0, int lane,
    const float* __restrict__ pegs_in,
    const int* __restrict__ n_pegs_in,
    const unsigned char* __restrict__ done_in,
    const float* __restrict__ tot_rew_in,
    const int* __restrict__ actions,
    const int* __restrict__ pos_ids,
    const int* __restrict__ mid_idx,
    const int* __restrict__ tgt_idx)
{
    const f32x4* src = (const f32x4*)(pegs_in + (size_t)ew0 * 33);
    #pragma unroll
    for (int k = 0; k < 8; ++k) T.r[k] = src[lane + 64 * k];   // 528 = 8*64+16
    if (lane < 16) T.r8 = src[512 + lane];
    const int e = ew0 + lane;
    T.a        = actions[e];
    T.np_new   = n_pegs_in[e] - 1;
    T.done_old = (done_in[e] != 0);
    T.tot      = tot_rew_in[e];
    T.p = pos_ids[T.a]; T.m = mid_idx[T.a]; T.g = tgt_idx[T.a];  // OOB->0
}

__device__ __forceinline__ void process_tile(
    const TileRegs& T, int ew0, int lane, int w,
    unsigned long long (*s_cm)[EPW + 1],
    unsigned long long (*s_bb)[EPW],
    float (*s_r1)[EPW], float (*s_r2)[EPW],
    float* __restrict__ out, int n)
{
    const int e = ew0 + lane;

    // Zero own accumulator slot. Same-wave DS ops are in-order: this zero
    // precedes the atomics below, and follows ALL prior-tile DS reads.
    s_cm[w][lane] = 0ull;

    const float rw  = (T.np_new == 1) ? 1.0f : (1.0f / 31.0f);
    const float npf = (float)T.np_new;
    out[e]                   = rw;            // rewards
    out[(size_t)182 * n + e] = npf;           // n_pegs
    out[(size_t)183 * n + e] = T.tot + rw;    // total_reward

    // Accumulate cell-mask bits (ds_or_b64 per chunk).
    {
        unsigned long long* cm = s_cm[w];
        #pragma unroll
        for (int k = 0; k < 8; ++k) {
            const int q   = lane + 64 * k;
            const int f   = q * 4;
            const int env = f / 33;                  // magic-mul (const div)
            const int c   = f - env * 33;
            const unsigned mm = (T.r[k][0] != 0.0f) | ((T.r[k][1] != 0.0f) << 1) |
                                ((T.r[k][2] != 0.0f) << 2) | ((T.r[k][3] != 0.0f) << 3);
            const unsigned long long full = (unsigned long long)mm << c;
            atomicOr(&cm[env], full & MASK33);
            const unsigned long long hi = full >> 33;
            if (hi) atomicOr(&cm[env + 1], hi);
        }
        if (lane < 16) {
            const int q   = 512 + lane;
            const int f   = q * 4;
            const int env = f / 33;
            const int c   = f - env * 33;
            const unsigned mm = (T.r8[0] != 0.0f) | ((T.r8[1] != 0.0f) << 1) |
                                ((T.r8[2] != 0.0f) << 2) | ((T.r8[3] != 0.0f) << 3);
            const unsigned long long full = (unsigned long long)mm << c;
            atomicOr(&cm[env], full & MASK33);
            const unsigned long long hi = full >> 33;
            if (hi) atomicOr(&cm[env + 1], hi);
        }
    }

    wave_lds_fence();   // all lanes' ORs complete

    // Patch jump in CELL space: order pos<-0, mid<-0, tgt<-1.
    unsigned long long cm = s_cm[w][lane];
    cm &= ~(1ull << T.p);
    cm &= ~(1ull << T.m);
    cm |=  (1ull << T.g);

    const unsigned long long P = cm_to_grid(cm);
    const unsigned long long E = ~P & B_MASK;
    const unsigned long long feas =
        (P & (P >> 1) & (E >> 2)  & C_LE4) |   // j+1
        (P & (P << 1) & (E << 2)  & C_GE2) |   // j-1
        (P & (P >> 7) & (E >> 14))         |   // i+1
        (P & (P << 7) & (E << 14));            // i-1

    const bool dn = (T.np_new == 1) | T.done_old | (feas == 0ull);
    out[(size_t)148 * n + e] = dn ? 1.0f : 0.0f;    // done

    s_cm[w][lane] = cm;                              // patched, for pegs-out
    s_bb[w][lane] = P;                               // grid, for states ch0
    s_r1[w][lane] = (npf - 1.0f)  * (1.0f / 31.0f);  // peg_ratio
    s_r2[w][lane] = (32.0f - npf) * (1.0f / 31.0f);  // removed_ratio

    wave_lds_fence();   // patched masks + ratios visible wave-wide

    // pegs out: regenerate from patched cell masks (values are {0,1}).
    {
        f32x4* dst = (f32x4*)(out + (size_t)149 * n + (size_t)ew0 * 33);
        #pragma unroll
        for (int k = 0; k < 9; ++k) {
            const int q = lane + 64 * k;
            if (k < 8 || lane < 16) {                // q < 528
                const int f   = q * 4;
                const int env = f / 33;              // magic-mul
                const int c   = f - env * 33;
                const unsigned long long cat =
                    s_cm[w][env] | (s_cm[w][env + 1] << 33);
                f32x4 v;
                #pragma unroll
                for (int rr = 0; rr < 4; ++rr)
                    v[rr] = (float)((unsigned int)(cat >> (c + rr)) & 1u);
                dst[q] = v;
            }
        }
    }

    // states (env,7,7,3): el = rc*3+ch; ch0 = grid bit rc; ch1/ch2 ratios.
    {
        f32x4* dst = (f32x4*)(out + (size_t)n + (size_t)ew0 * 147);
        const int total = EPW * 147 / 4;              // 2352
        for (int q = lane; q < total; q += 64) {
            const int f4 = q * 4;
            int env = f4 / 147;                       // magic-mul
            int el  = f4 - env * 147;
            unsigned long long bb = s_bb[w][env];
            float r1 = s_r1[w][env], r2 = s_r2[w][env];
            f32x4 v;
            #pragma unroll
            for (int rr = 0; rr < 4; ++rr) {
                if (el == 147) {                      // env boundary
                    el = 0; ++env;
                    bb = s_bb[w][env]; r1 = s_r1[w][env]; r2 = s_r2[w][env];
                }
                const int rc = el / 3;                // magic-mul
                const int ch = el - rc * 3;
                v[rr] = (ch == 0) ? (float)((unsigned int)(bb >> rc) & 1u)
                                  : ((ch == 1) ? r1 : r2);
                ++el;
            }
            dst[q] = v;
        }
    }
}

__global__ __launch_bounds__(NTH) void peg_step(
    const float* __restrict__ pegs_in,
    const int* __restrict__ n_pegs_in,
    const unsigned char* __restrict__ done_in,
    const float* __restrict__ tot_rew_in,
    const int* __restrict__ actions,
    const int* __restrict__ pos_ids,
    const int* __restrict__ mid_idx,
    const int* __restrict__ tgt_idx,
    float* __restrict__ out,
    int n)
{
    __shared__ unsigned long long s_cm[WPB][EPW + 1];   // cell masks (+pad)
    __shared__ unsigned long long s_bb[WPB][EPW];       // grid masks
    __shared__ float s_r1[WPB][EPW], s_r2[WPB][EPW];

    const int t    = threadIdx.x;
    const int w    = t >> 6;
    const int lane = t & 63;
    // Each wave owns TPW consecutive 64-env tiles.
    const int ewA  = (blockIdx.x * WPB + w) * (TPW * EPW);
    const int ewB  = ewA + EPW;

    // ---- Pipeline: issue BOTH tiles' loads up front (independent register
    //      sets). The compiler emits counted vmcnt waits for A's regs while
    //      B's loads stay in flight -> B's reads overlap A's stores.
    TileRegs A, B;
    load_tile(A, ewA, lane, pegs_in, n_pegs_in, done_in, tot_rew_in,
              actions, pos_ids, mid_idx, tgt_idx);
    load_tile(B, ewB, lane, pegs_in, n_pegs_in, done_in, tot_rew_in,
              actions, pos_ids, mid_idx, tgt_idx);

    process_tile(A, ewA, lane, w, s_cm, s_bb, s_r1, s_r2, out, n);
    process_tile(B, ewB, lane, w, s_cm, s_bb, s_r1, s_r2, out, n);
}

extern "C" void kernel_launch(void* const* d_in, const int* in_sizes, int n_in,
                              void* d_out, int out_size, void* d_ws, size_t ws_size,
                              hipStream_t stream) {
    const float* pegs          = (const float*)d_in[0];
    const int* n_pegs          = (const int*)d_in[1];
    const unsigned char* done  = (const unsigned char*)d_in[2];
    const float* total_reward  = (const float*)d_in[3];
    const int* actions         = (const int*)d_in[4];
    const int* pos_ids         = (const int*)d_in[5];
    const int* mid_idx         = (const int*)d_in[6];
    const int* tgt_idx         = (const int*)d_in[7];
    // d_in[8] oob_mask, d_in[9] i_ind, d_in[10] j_ind: unused.
    float* out = (float*)d_out;

    int n = in_sizes[1];                    // 262144, divisible by 512
    dim3 grid(n / (WPB * EPW * TPW)), block(NTH);   // 512 blocks
    hipLaunchKernelGGL(peg_step, grid, block, 0, stream,
                       pegs, n_pegs, done, total_reward, actions,
                       pos_ids, mid_idx, tgt_idx, out, n);
}

// Round 12
// 44.777 us; speedup vs baseline: 1.1465x; 1.0559x over previous
//
#include <hip/hip_runtime.h>

// Peg-solitaire batched env step — per-WAVE pipeline edition (R5 verbatim,
// best measured: 44.54 us). n = 262144. Each 64-lane wave owns 64 envs
// end-to-end; NO __syncthreads (no vmcnt drain, no cross-wave rendezvous).
// Intra-wave LDS visibility via s_waitcnt lgkmcnt(0).
//
// Session ledger (why this shape): nt stores -15% (R8); fission +3.5 (R9);
// reg-forward+vmcnt(0) +3.4 (R6); 2-tile pipeline +2.8 (R10); atomic
// cell-mask neutral (R7); block barriers +0.9 (R1). 232 MB mandatory traffic
// at 5.2 TB/s effective = 83% of copy ceiling (mixed-stream turnaround).
//
// Inputs: 0 pegs f32(n,33) | 1 n_pegs i32(n) | 2 done bool(n)
//         3 total_reward f32(n) | 4 actions i32(n)
//         5 pos_ids(132) | 6 mid_idx(132) | 7 tgt_idx(132) (OOB->0 encoded)
//         8 oob (unused) | 9 i_ind(33) | 10 j_ind(33)
// Output flat f32 (184n): rewards[0,n) | states[n,148n) | done[148n,149n)
//  | pegs[149n,182n) | n_pegs[182n,183n) | total_reward[183n,184n)

#define NTH 256
#define WPB 4      // waves per block
#define EPW 64     // envs per wave

typedef float f32x4 __attribute__((ext_vector_type(4)));

// cell k -> grid bit (i*7+j); used ONLY with compile-time (unrolled) indices.
__device__ constexpr int C2B[33] = {
    24,  2,  3,  4,  9, 10, 11, 14, 15, 16, 17, 18, 19, 20,
    21, 22, 23, 25, 26, 27, 28, 29, 30, 31, 32, 33, 34,
    37, 38, 39, 44, 45, 46};

constexpr unsigned long long cross_mask() {
    unsigned long long b = 0;
    for (int i = 0; i < 7; ++i)
        for (int j = 0; j < 7; ++j)
            if ((i >= 2 && i <= 4) || (j >= 2 && j <= 4))
                b |= 1ull << (i * 7 + j);
    return b;
}
constexpr unsigned long long cols_le(int jmax) {
    unsigned long long b = 0;
    for (int i = 0; i < 7; ++i)
        for (int j = 0; j <= jmax; ++j) b |= 1ull << (i * 7 + j);
    return b;
}
constexpr unsigned long long cols_ge(int jmin) {
    unsigned long long b = 0;
    for (int i = 0; i < 7; ++i)
        for (int j = jmin; j < 7; ++j) b |= 1ull << (i * 7 + j);
    return b;
}
constexpr unsigned long long B_MASK = cross_mask();
constexpr unsigned long long C_LE4  = cols_le(4);   // sources of j+1 jumps
constexpr unsigned long long C_GE2  = cols_ge(2);   // sources of j-1 jumps

// Intra-wave LDS fence: all prior ds ops by this wave complete & visible.
__device__ __forceinline__ void wave_lds_fence() {
    asm volatile("s_waitcnt lgkmcnt(0)" ::: "memory");
    __builtin_amdgcn_sched_barrier(0);   // rule #18 insurance
}

__global__ __launch_bounds__(NTH) void peg_step(
    const float* __restrict__ pegs_in,
    const int* __restrict__ n_pegs_in,
    const unsigned char* __restrict__ done_in,
    const float* __restrict__ tot_rew_in,
    const int* __restrict__ actions,
    const int* __restrict__ pos_ids,
    const int* __restrict__ mid_idx,
    const int* __restrict__ tgt_idx,
    const int* __restrict__ i_ind,
    const int* __restrict__ j_ind,
    float* __restrict__ out,
    int n)
{
    __shared__ __align__(16) float s_pegs[WPB][EPW * 33];   // 33.8 KB
    __shared__ unsigned long long s_bb[WPB][EPW];
    __shared__ float s_r1[WPB][EPW], s_r2[WPB][EPW];

    const int t    = threadIdx.x;
    const int w    = t >> 6;
    const int lane = t & 63;
    const int ew0  = blockIdx.x * (WPB * EPW) + w * EPW;   // wave's first env
    const int e    = ew0 + lane;

    // ---- Phase A: stage this wave's 64 rows (8448 B contiguous) into its
    //      own LDS segment, coalesced f4 through VGPRs (R1-proven pattern).
    {
        const f32x4* src = (const f32x4*)(pegs_in + (size_t)ew0 * 33);
        f32x4* dst = (f32x4*)s_pegs[w];
        #pragma unroll
        for (int i = lane; i < EPW * 33 / 4; i += 64) dst[i] = src[i];
    }

    // ---- Per-env scalars + tiny L1-resident tables (overlap staging).
    const int a         = actions[e];
    const int np_new    = n_pegs_in[e] - 1;
    const bool done_old = (done_in[e] != 0);
    const float tot     = tot_rew_in[e];
    const int p = pos_ids[a], m = mid_idx[a], g = tgt_idx[a];   // OOB->0
    const int bp = i_ind[p] * 7 + j_ind[p];
    const int bm = i_ind[m] * 7 + j_ind[m];
    const int bg = i_ind[g] * 7 + j_ind[g];

    const float rw  = (np_new == 1) ? 1.0f : (1.0f / 31.0f);
    const float npf = (float)np_new;
    out[e]                   = rw;          // rewards
    out[(size_t)182 * n + e] = npf;         // n_pegs
    out[(size_t)183 * n + e] = tot + rw;    // total_reward

    wave_lds_fence();   // staged rows visible wave-wide

    // ---- Phase B: own-row bitboard (compile-time shifts), patch LDS + P.
    float* row = s_pegs[w] + lane * 33;
    unsigned long long P = 0;
    #pragma unroll
    for (int c = 0; c < 33; ++c)
        P |= (unsigned long long)(row[c] != 0.0f) << C2B[c];

    // write order pos<-0, mid<-0, tgt<-1 (aliasing when OOB defaults to 0)
    row[p] = 0.0f;
    row[m] = 0.0f;
    row[g] = 1.0f;
    P &= ~(1ull << bp);
    P &= ~(1ull << bm);
    P |=  (1ull << bg);

    // ---- Feasibility over all 132 actions in ~15 wide ops
    const unsigned long long E = ~P & B_MASK;
    const unsigned long long feas =
        (P & (P >> 1) & (E >> 2)  & C_LE4) |   // j+1
        (P & (P << 1) & (E << 2)  & C_GE2) |   // j-1
        (P & (P >> 7) & (E >> 14))         |   // i+1
        (P & (P << 7) & (E << 14));            // i-1

    const bool dn = (np_new == 1) | done_old | (feas == 0ull);
    out[(size_t)148 * n + e] = dn ? 1.0f : 0.0f;    // done

    s_bb[w][lane] = P;
    s_r1[w][lane] = (npf - 1.0f)  * (1.0f / 31.0f);   // peg_ratio
    s_r2[w][lane] = (32.0f - npf) * (1.0f / 31.0f);   // removed_ratio

    wave_lds_fence();   // patches + bb/ratios visible wave-wide

    // ---- Phase C: stream pegs out (coalesced f4 from this wave's segment).
    {
        const f32x4* src = (const f32x4*)s_pegs[w];
        f32x4* dst = (f32x4*)(out + (size_t)149 * n + (size_t)ew0 * 33);
        #pragma unroll
        for (int i = lane; i < EPW * 33 / 4; i += 64) dst[i] = src[i];
    }

    // ---- Phase D: states (env,7,7,3) for this wave's 64 envs, coalesced f4.
    //      el = rc*3+ch; ch0 = grid bit rc of bb; ch1/ch2 = ratios.
    {
        f32x4* dst = (f32x4*)(out + (size_t)n + (size_t)ew0 * 147);
        const int total = EPW * 147 / 4;              // 2352
        for (int q = lane; q < total; q += 64) {
            const int f4 = q * 4;
            int env = f4 / 147;                       // magic-mul
            int el  = f4 - env * 147;
            unsigned long long bb = s_bb[w][env];
            float r1 = s_r1[w][env], r2 = s_r2[w][env];
            f32x4 v;
            #pragma unroll
            for (int r = 0; r < 4; ++r) {
                if (el == 147) {                      // env boundary
                    el = 0; ++env;
                    bb = s_bb[w][env]; r1 = s_r1[w][env]; r2 = s_r2[w][env];
                }
                const int rc = el / 3;                // magic-mul
                const int ch = el - rc * 3;
                v[r] = (ch == 0) ? (float)((unsigned int)(bb >> rc) & 1u)
                                 : ((ch == 1) ? r1 : r2);
                ++el;
            }
            dst[q] = v;
        }
    }
}

extern "C" void kernel_launch(void* const* d_in, const int* in_sizes, int n_in,
                              void* d_out, int out_size, void* d_ws, size_t ws_size,
                              hipStream_t stream) {
    const float* pegs          = (const float*)d_in[0];
    const int* n_pegs          = (const int*)d_in[1];
    const unsigned char* done  = (const unsigned char*)d_in[2];
    const float* total_reward  = (const float*)d_in[3];
    const int* actions         = (const int*)d_in[4];
    const int* pos_ids         = (const int*)d_in[5];
    const int* mid_idx         = (const int*)d_in[6];
    const int* tgt_idx         = (const int*)d_in[7];
    // d_in[8] oob_mask unused (tables already encode OOB->0)
    const int* i_ind           = (const int*)d_in[9];
    const int* j_ind           = (const int*)d_in[10];
    float* out = (float*)d_out;

    int n = in_sizes[1];                    // 262144, divisible by 256
    dim3 grid(n / (WPB * EPW)), block(NTH);
    hipLaunchKernelGGL(peg_step, grid, block, 0, stream,
                       pegs, n_pegs, done, total_reward, actions,
                       pos_ids, mid_idx, tgt_idx, i_ind, j_ind, out, n);
}